// Round 7
// baseline (135.294 us; speedup 1.0000x reference)
//
#include <hip/hip_runtime.h>
#include <math.h>

#define Bq 16
#define Tq 81
#define Dq 128
#define Hq 8
#define BT (Bq*Tq)          // 1296
#define BTD (Bq*Tq*Dq)      // 165888 (out region 0)
#define PS 84               // padded s-stride of P
// ws layout (floats). P: [b][t][h][s(pad 84)]; Q/V: [b][h][t][d]
#define P_SZ   (Bq*Tq*Hq*PS)        // 870912
#define QV_SZ  (BT*Hq*Dq)           // 1327104
#define P_OFF  0
#define Q_OFF  (P_OFF + P_SZ)
#define V_OFF  (Q_OFF + QV_SZ)

typedef __attribute__((ext_vector_type(8))) short short8;
typedef __attribute__((ext_vector_type(4))) float f32x4;

__device__ __forceinline__ float l1_4(const float4 q, const float4 k) {
    return fabsf(q.x - k.x) + fabsf(q.y - k.y) + fabsf(q.z - k.z) + fabsf(q.w - k.w);
}
__device__ __forceinline__ int imin(int a, int b) { return a < b ? a : b; }
__device__ __forceinline__ unsigned short f2bf(float f) {   // RNE f32 -> bf16
    unsigned u = __float_as_uint(f);
    u += 0x7fffu + ((u >> 16) & 1u);
    return (unsigned short)(u >> 16);
}
__device__ __forceinline__ short8 cvt8(const float4 a, const float4 b) {
    short8 r;
    r[0] = (short)f2bf(a.x); r[1] = (short)f2bf(a.y);
    r[2] = (short)f2bf(a.z); r[3] = (short)f2bf(a.w);
    r[4] = (short)f2bf(b.x); r[5] = (short)f2bf(b.y);
    r[6] = (short)f2bf(b.z); r[7] = (short)f2bf(b.w);
    return r;
}

// ---------------------------------------------------------------------------
// K1: QKV GEMM via bf16 MFMA 16x16x32, f32->bf16 conversion fused in-register
// (redundant W conversion is ~0.26 us chip-wide — cheaper than a k_prep
// launch + ws round-trip). grid (21, 32), 256 thr = 4 waves.
// Wave w: m-tile mt = bx*4+w (16 rows of b*t), n-range n0 = by*64.
// by = h*4 + isV*2 + half. C/D map: col=lane&15, row=quad*4+reg.
// Epilogue: +bias, *he for V, stores Q/V in [b][h][t][d].
// ---------------------------------------------------------------------------
__global__ __launch_bounds__(256) void k_qkv_mfma(
    const float* __restrict__ x, const float* __restrict__ wqkv,
    const float* __restrict__ bias, const float* __restrict__ he,
    float* __restrict__ Qo, float* __restrict__ Vo)
{
    const int tid = threadIdx.x;
    const int w = tid >> 6, lane = tid & 63;
    const int ln = lane & 15, quad = lane >> 4;
    const int mt = blockIdx.x * 4 + w;            // 0..83; 81..83 tail pads
    const int n0 = blockIdx.y * 64;
    const int h  = blockIdx.y >> 2;
    const int isV = (blockIdx.y >> 1) & 1;
    const int c0 = (blockIdx.y & 1) * 64;

    const int row = mt * 16 + ln;
    const int arow = row < BT ? row : BT - 1;
    const float* xa = x + (size_t)arow * Dq + quad * 8;
    const float* wb0 = wqkv + (size_t)(n0 + ln) * Dq + quad * 8;

    f32x4 acc[4];
    #pragma unroll
    for (int i = 0; i < 4; ++i) acc[i] = (f32x4){0.f, 0.f, 0.f, 0.f};

    #pragma unroll
    for (int kb = 0; kb < Dq; kb += 32) {
        const short8 af = cvt8(*(const float4*)(xa + kb),
                               *(const float4*)(xa + kb + 4));
        #pragma unroll
        for (int nt = 0; nt < 4; ++nt) {
            const float* wr = wb0 + (size_t)(nt * 16) * Dq + kb;
            const short8 bf = cvt8(*(const float4*)(wr),
                                   *(const float4*)(wr + 4));
            acc[nt] = __builtin_amdgcn_mfma_f32_16x16x32_bf16(af, bf, acc[nt], 0, 0, 0);
        }
    }

    if (mt >= 81) return;
    const float scale = isV ? he[h] : 1.0f;
    float* dst = isV ? Vo : Qo;
    const int gm0 = mt * 16 + quad * 4;           // <= 1292
    #pragma unroll
    for (int nt = 0; nt < 4; ++nt) {
        const float bn = bias[n0 + nt * 16 + ln];
        #pragma unroll
        for (int r = 0; r < 4; ++r) {
            const int gm = gm0 + r;
            const int bb = gm / 81, tt = gm - bb * 81;
            dst[(((size_t)bb * Hq + h) * Tq + tt) * Dq + c0 + nt * 16 + ln] =
                (acc[nt][r] + bn) * scale;
        }
    }
}

// ---------------------------------------------------------------------------
// K2: scores + softmax + P (+ap for b==0). grid (4, 8, 16) = (tq, h, b),
// block 256. K = x*wk in LDS (81x132). Compute: 243 threads = 3 tg (7t) x
// 81 sg (1s) -> 1 ds_read_b128 per k4 per thread, q loads wave-broadcast,
// 95% thread utilization. Wave-parallel softmax. P store [b][t][h][s]
// coalesced; ap fused for b==0.
// ---------------------------------------------------------------------------
__global__ __launch_bounds__(256) void k_scores(
    const float* __restrict__ x, const float* __restrict__ Q,
    const float* __restrict__ wk, const float* __restrict__ msk,
    float* __restrict__ P, float* __restrict__ out)
{
    __shared__ float Kl[81 * 132];
    __shared__ float sc[21 * 85];
    __shared__ float rsum[24];
    const int tid = threadIdx.x;
    const int tq = blockIdx.x, h = blockIdx.y, b = blockIdx.z;
    const int t0g = tq * 21;
    const int nt = (tq == 3) ? 18 : 21;

    // stage K = x * wk[h]  (81 rows x 128, row stride 132)
    {
        const float* wkb = wk + (size_t)h * Dq;
        for (int idx = tid; idx < Tq * 32; idx += 256) {
            const int r = idx >> 5, c = idx & 31;
            const float4 xv = *(const float4*)(x + (size_t)(b * Tq + r) * Dq + c * 4);
            const float4 wv = *(const float4*)(wkb + c * 4);
            float4 kv;
            kv.x = xv.x * wv.x; kv.y = xv.y * wv.y;
            kv.z = xv.z * wv.z; kv.w = xv.w * wv.w;
            *(float4*)(&Kl[r * 132 + c * 4]) = kv;
        }
    }
    __syncthreads();

    if (tid < 243) {
        const int tg = tid / 81, sg = tid % 81;   // tg 0..2, sg = s
        const float* qrow[7];
        #pragma unroll
        for (int i = 0; i < 7; ++i) {
            const int t = imin(t0g + tg * 7 + i, Tq - 1);
            qrow[i] = Q + (((size_t)b * Hq + h) * Tq + t) * Dq;
        }
        float acc[7];
        #pragma unroll
        for (int i = 0; i < 7; ++i) acc[i] = 0.f;

        #pragma unroll 4
        for (int k4 = 0; k4 < 32; ++k4) {
            const float4 kv = *(const float4*)(&Kl[sg * 132 + k4 * 4]);
            #pragma unroll
            for (int i = 0; i < 7; ++i) {
                const float4 qv = *(const float4*)(qrow[i] + k4 * 4);
                acc[i] += l1_4(qv, kv);
            }
        }
        const float ns = -0.08838834764831845f;   // -1/sqrt(128)
        #pragma unroll
        for (int i = 0; i < 7; ++i)
            sc[(tg * 7 + i) * 85 + sg] = acc[i] * ns;
    }
    __syncthreads();

    // wave-parallel softmax: wave w handles rows w, w+4, ...
    {
        const int w = tid >> 6, lane = tid & 63;
        for (int r = w; r < nt; r += 4) {
            float* row = sc + r * 85;
            const bool hi = (lane + 64) < Tq;
            const float v0 = row[lane];
            const float v1 = hi ? row[lane + 64] : -1e30f;
            float m = fmaxf(v0, v1);
            #pragma unroll
            for (int off = 32; off > 0; off >>= 1)
                m = fmaxf(m, __shfl_xor(m, off));
            const float e0 = __expf(v0 - m);
            const float e1 = hi ? __expf(v1 - m) : 0.f;
            float s = e0 + e1;
            #pragma unroll
            for (int off = 32; off > 0; off >>= 1)
                s += __shfl_xor(s, off);
            row[lane] = e0;
            if (hi) row[lane + 64] = e1;
            if (lane == 0) rsum[r] = 1.0f / s;
        }
    }
    __syncthreads();

    // store P[b][t][h][s] (coalesced s-runs) + fused ap for b==0
    const bool doap = (b == 0);
    for (int idx = tid; idx < nt * Tq; idx += 256) {
        const int tl = idx / Tq, s = idx - tl * Tq;
        const int tg2 = t0g + tl;
        const float mv = msk[((size_t)h * Tq + tg2) * Tq + s];
        const float pm = sc[tl * 85 + s] * rsum[tl] * mv;
        P[(((size_t)b * Tq + tg2) * Hq + h) * PS + s] = pm;
        if (doap) out[BTD + ((size_t)tg2 * Tq + s) * Hq + h] = pm - 1.0f + mv;
    }
}

// ---------------------------------------------------------------------------
// K3: bo einsum + quick-gelu + fanout + residual. grid (11, 16) = (t-chunk8, b),
// block 512 = 8 waves; wave w = head w, lanes = d/2 (one wave V read = one
// contiguous 512B row, V layout [b][h][s][d]). P tile [8t][8h][84s] staged
// contiguously; s blocked by 4. 8-way LDS reduce -> gelu -> fanout.
// ---------------------------------------------------------------------------
__global__ __launch_bounds__(512) void k_out(
    const float* __restrict__ x, const float* __restrict__ P,
    const float* __restrict__ V, const float* __restrict__ fw,
    const float* __restrict__ fb, float* __restrict__ out)
{
    __shared__ float Pl[8][Hq][PS];          // 21.5 KB
    __shared__ float bo_part[8][8][128];     // 32 KB
    __shared__ float zs[8][128];             // 4 KB
    const int tid = threadIdx.x;
    const int t0 = blockIdx.x * 8, b = blockIdx.y;

    // stage P tile: 5376 contiguous floats (last block over-reads into Q
    // region — finite, masked at store)
    {
        const float4* src = (const float4*)(P + ((size_t)b * Tq + t0) * Hq * PS);
        #pragma unroll
        for (int idx = tid; idx < 8 * Hq * PS / 4; idx += 512)
            ((float4*)Pl)[idx] = src[idx];
    }
    __syncthreads();

    const int w = tid >> 6, lane = tid & 63;   // w = head
    {
        const int d0 = lane * 2;
        float2 acc[8];
        #pragma unroll
        for (int i = 0; i < 8; ++i) acc[i] = make_float2(0.f, 0.f);
        const float* vp = V + (((size_t)b * Hq + w) * Tq) * Dq + d0;
        for (int s4 = 0; s4 < 20; ++s4) {
            float4 p[8];
            #pragma unroll
            for (int t = 0; t < 8; ++t)
                p[t] = *(const float4*)(&Pl[t][w][s4 * 4]);
            #pragma unroll
            for (int ss = 0; ss < 4; ++ss) {
                const int s = s4 * 4 + ss;
                const float2 vv = *(const float2*)(vp + (size_t)s * Dq);
                #pragma unroll
                for (int t = 0; t < 8; ++t) {
                    const float pv = ((const float*)&p[t])[ss];
                    acc[t].x = fmaf(pv, vv.x, acc[t].x);
                    acc[t].y = fmaf(pv, vv.y, acc[t].y);
                }
            }
        }
        {   // tail s = 80
            const float2 vv = *(const float2*)(vp + (size_t)80 * Dq);
            #pragma unroll
            for (int t = 0; t < 8; ++t) {
                const float pv = Pl[t][w][80];
                acc[t].x = fmaf(pv, vv.x, acc[t].x);
                acc[t].y = fmaf(pv, vv.y, acc[t].y);
            }
        }
        #pragma unroll
        for (int t = 0; t < 8; ++t) {
            bo_part[w][t][d0]     = acc[t].x;
            bo_part[w][t][d0 + 1] = acc[t].y;
        }
    }
    __syncthreads();

    #pragma unroll
    for (int idx = tid; idx < 1024; idx += 512) {   // gelu: 8t x 128d
        const int t = idx >> 7, d = idx & 127;
        float bo = 0.f;
        #pragma unroll
        for (int ww = 0; ww < 8; ++ww) bo += bo_part[ww][t][d];
        const float tt = bo + 4.0f;
        const float sg = 1.0f / (1.0f + __expf(-1.702f * tt));
        zs[t][d] = tt * sg - 4.0f;
    }
    __syncthreads();

    {   // fanout: thread -> (n = tid&127), t in {tg, tg+4}; fw row shared
        const int n = tid & 127, tg = tid >> 7;
        const float* fwr = fw + (size_t)n * Dq;
        const float fbn = fb[n];
        float a0 = 0.f, a1 = 0.f;
        #pragma unroll 8
        for (int k4 = 0; k4 < 32; ++k4) {
            const float4 w4 = *(const float4*)(fwr + k4 * 4);
            const float4 z0 = *(const float4*)(&zs[tg][k4 * 4]);
            const float4 z1 = *(const float4*)(&zs[tg + 4][k4 * 4]);
            a0 += z0.x * w4.x + z0.y * w4.y + z0.z * w4.z + z0.w * w4.w;
            a1 += z1.x * w4.x + z1.y * w4.y + z1.z * w4.z + z1.w * w4.w;
        }
        const int t1 = t0 + tg, t2 = t0 + tg + 4;
        if (t1 < Tq) {
            const size_t o = ((size_t)b * Tq + t1) * Dq + n;
            out[o] = x[o] + a0 + fbn;
        }
        if (t2 < Tq) {
            const size_t o = ((size_t)b * Tq + t2) * Dq + n;
            out[o] = x[o] + a1 + fbn;
        }
    }
}

extern "C" void kernel_launch(void* const* d_in, const int* in_sizes, int n_in,
                              void* d_out, int out_size, void* d_ws, size_t ws_size,
                              hipStream_t stream) {
    const float* x        = (const float*)d_in[0];
    const float* msk      = (const float*)d_in[1];
    const float* wqkv_w   = (const float*)d_in[2];
    const float* wqkv_b   = (const float*)d_in[3];
    const float* wk_w     = (const float*)d_in[4];
    const float* fanout_w = (const float*)d_in[5];
    const float* fanout_b = (const float*)d_in[6];
    const float* he       = (const float*)d_in[7];
    float* out = (float*)d_out;
    float* ws  = (float*)d_ws;

    float* P   = ws + P_OFF;
    float* Q   = ws + Q_OFF;
    float* V   = ws + V_OFF;

    k_qkv_mfma<<<dim3(21, 32), 256, 0, stream>>>(x, wqkv_w, wqkv_b, he, Q, V);
    k_scores<<<dim3(4, 8, 16), 256, 0, stream>>>(x, Q, wk_w, msk, P, out);
    k_out<<<dim3(11, 16), 512, 0, stream>>>(x, P, V, fanout_w, fanout_b, out);
}

// Round 8
// 126.152 us; speedup vs baseline: 1.0725x; 1.0725x over previous
//
#include <hip/hip_runtime.h>
#include <math.h>

#define Bq 16
#define Tq 81
#define Dq 128
#define Hq 8
#define BT (Bq*Tq)          // 1296
#define BTD (Bq*Tq*Dq)      // 165888 (out region 0)
#define PS 84               // padded s-stride of P
// ws layout (floats). P: [b][t][h][s(pad 84)]; Q/V: [b][h][t][d]
#define P_SZ   (Bq*Tq*Hq*PS)        // 870912
#define QV_SZ  (BT*Hq*Dq)           // 1327104
#define P_OFF  0
#define Q_OFF  (P_OFF + P_SZ)
#define V_OFF  (Q_OFF + QV_SZ)

#define LSTR 136            // LDS row stride (ushorts): 272 B, 16B-aligned rows

typedef __attribute__((ext_vector_type(8))) short short8;
typedef __attribute__((ext_vector_type(4))) float f32x4;

__device__ __forceinline__ float l1_4(const float4 q, const float4 k) {
    return fabsf(q.x - k.x) + fabsf(q.y - k.y) + fabsf(q.z - k.z) + fabsf(q.w - k.w);
}
__device__ __forceinline__ int imin(int a, int b) { return a < b ? a : b; }
__device__ __forceinline__ unsigned short f2bf(float f) {   // RNE f32 -> bf16
    unsigned u = __float_as_uint(f);
    u += 0x7fffu + ((u >> 16) & 1u);
    return (unsigned short)(u >> 16);
}

// ---------------------------------------------------------------------------
// K1: QKV GEMM via bf16 MFMA 16x16x32. grid (21, 32), 256 thr = 4 waves.
// f32->bf16 conversion done ONCE per block into LDS (R7's in-loop cvt put a
// load+cvt chain on every MFMA's critical path — regressed; this decouples).
// Block: 64 m-rows (bx*64, clamped/masked at tail) x 64 W-rows (by*64).
// Wave w: local m-tile w (16 rows), 4 n-tiles. C/D: col=lane&15, row=quad*4+reg.
// Epilogue: +bias, *he for V, stores Q/V in [b][h][t][d].
// ---------------------------------------------------------------------------
__global__ __launch_bounds__(256) void k_qkv_mfma(
    const float* __restrict__ x, const float* __restrict__ wqkv,
    const float* __restrict__ bias, const float* __restrict__ he,
    float* __restrict__ Qo, float* __restrict__ Vo)
{
    __shared__ unsigned short xs[64 * LSTR];    // 17.4 KB
    __shared__ unsigned short wsh[64 * LSTR];   // 17.4 KB
    const int tid = threadIdx.x;
    const int w = tid >> 6, lane = tid & 63;
    const int ln = lane & 15, quad = lane >> 4;
    const int r0 = blockIdx.x * 64;               // m-row base (bx 0..20)
    const int n0 = blockIdx.y * 64;               // W-row base
    const int h  = blockIdx.y >> 2;
    const int isV = (blockIdx.y >> 1) & 1;
    const int c0 = (blockIdx.y & 1) * 64;

    // stage + cvt: 64 x-rows and 64 W-rows (8192 floats each, 8 float4/thread)
    #pragma unroll
    for (int i = 0; i < 8; ++i) {
        const int idx = tid + i * 256;            // 0..2047
        const int r = idx >> 5, c4 = idx & 31;
        const int gr = imin(r0 + r, BT - 1);      // clamp tail rows
        const float4 v = *(const float4*)(x + (size_t)gr * Dq + c4 * 4);
        ushort4 o;
        o.x = f2bf(v.x); o.y = f2bf(v.y); o.z = f2bf(v.z); o.w = f2bf(v.w);
        *(ushort4*)(&xs[r * LSTR + c4 * 4]) = o;

        const float4 vw = *(const float4*)(wqkv + (size_t)(n0 + r) * Dq + c4 * 4);
        ushort4 ow;
        ow.x = f2bf(vw.x); ow.y = f2bf(vw.y); ow.z = f2bf(vw.z); ow.w = f2bf(vw.w);
        *(ushort4*)(&wsh[r * LSTR + c4 * 4]) = ow;
    }
    __syncthreads();

    const unsigned short* xa = xs + (w * 16 + ln) * LSTR + quad * 8;
    const unsigned short* wb = wsh + ln * LSTR + quad * 8;

    f32x4 acc[4];
    #pragma unroll
    for (int i = 0; i < 4; ++i) acc[i] = (f32x4){0.f, 0.f, 0.f, 0.f};

    #pragma unroll
    for (int kb = 0; kb < Dq; kb += 32) {
        const short8 af = *(const short8*)(xa + kb);
        #pragma unroll
        for (int nt = 0; nt < 4; ++nt) {
            const short8 bf = *(const short8*)(wb + nt * 16 * LSTR + kb);
            acc[nt] = __builtin_amdgcn_mfma_f32_16x16x32_bf16(af, bf, acc[nt], 0, 0, 0);
        }
    }

    const float scale = isV ? he[h] : 1.0f;
    float* dst = isV ? Vo : Qo;
    const int gm0 = r0 + w * 16 + quad * 4;
    #pragma unroll
    for (int nt = 0; nt < 4; ++nt) {
        const float bn = bias[n0 + nt * 16 + ln];
        #pragma unroll
        for (int r = 0; r < 4; ++r) {
            const int gm = gm0 + r;
            if (gm < BT) {
                const int bb = gm / 81, tt = gm - bb * 81;
                dst[(((size_t)bb * Hq + h) * Tq + tt) * Dq + c0 + nt * 16 + ln] =
                    (acc[nt][r] + bn) * scale;
            }
        }
    }
}

// ---------------------------------------------------------------------------
// K2: scores + softmax + P (+ap for b==0). grid (4, 8, 16) = (tq, h, b),
// block 256. K = x*wk in LDS (81x132). Compute: 243 threads = 3 tg (7t) x
// 81 sg (1s) -> 1 ds_read_b128 per k4 per thread, q loads wave-broadcast.
// Wave-parallel softmax. P store [b][t][h][s] coalesced; ap fused for b==0.
// ---------------------------------------------------------------------------
__global__ __launch_bounds__(256) void k_scores(
    const float* __restrict__ x, const float* __restrict__ Q,
    const float* __restrict__ wk, const float* __restrict__ msk,
    float* __restrict__ P, float* __restrict__ out)
{
    __shared__ float Kl[81 * 132];
    __shared__ float sc[21 * 85];
    __shared__ float rsum[24];
    const int tid = threadIdx.x;
    const int tq = blockIdx.x, h = blockIdx.y, b = blockIdx.z;
    const int t0g = tq * 21;
    const int nt = (tq == 3) ? 18 : 21;

    // stage K = x * wk[h]  (81 rows x 128, row stride 132)
    {
        const float* wkb = wk + (size_t)h * Dq;
        for (int idx = tid; idx < Tq * 32; idx += 256) {
            const int r = idx >> 5, c = idx & 31;
            const float4 xv = *(const float4*)(x + (size_t)(b * Tq + r) * Dq + c * 4);
            const float4 wv = *(const float4*)(wkb + c * 4);
            float4 kv;
            kv.x = xv.x * wv.x; kv.y = xv.y * wv.y;
            kv.z = xv.z * wv.z; kv.w = xv.w * wv.w;
            *(float4*)(&Kl[r * 132 + c * 4]) = kv;
        }
    }
    __syncthreads();

    if (tid < 243) {
        const int tg = tid / 81, sg = tid % 81;   // tg 0..2, sg = s
        const float* qrow[7];
        #pragma unroll
        for (int i = 0; i < 7; ++i) {
            const int t = imin(t0g + tg * 7 + i, Tq - 1);
            qrow[i] = Q + (((size_t)b * Hq + h) * Tq + t) * Dq;
        }
        float acc[7];
        #pragma unroll
        for (int i = 0; i < 7; ++i) acc[i] = 0.f;

        #pragma unroll 4
        for (int k4 = 0; k4 < 32; ++k4) {
            const float4 kv = *(const float4*)(&Kl[sg * 132 + k4 * 4]);
            #pragma unroll
            for (int i = 0; i < 7; ++i) {
                const float4 qv = *(const float4*)(qrow[i] + k4 * 4);
                acc[i] += l1_4(qv, kv);
            }
        }
        const float ns = -0.08838834764831845f;   // -1/sqrt(128)
        #pragma unroll
        for (int i = 0; i < 7; ++i)
            sc[(tg * 7 + i) * 85 + sg] = acc[i] * ns;
    }
    __syncthreads();

    // wave-parallel softmax: wave w handles rows w, w+4, ...
    {
        const int w = tid >> 6, lane = tid & 63;
        for (int r = w; r < nt; r += 4) {
            float* row = sc + r * 85;
            const bool hi = (lane + 64) < Tq;
            const float v0 = row[lane];
            const float v1 = hi ? row[lane + 64] : -1e30f;
            float m = fmaxf(v0, v1);
            #pragma unroll
            for (int off = 32; off > 0; off >>= 1)
                m = fmaxf(m, __shfl_xor(m, off));
            const float e0 = __expf(v0 - m);
            const float e1 = hi ? __expf(v1 - m) : 0.f;
            float s = e0 + e1;
            #pragma unroll
            for (int off = 32; off > 0; off >>= 1)
                s += __shfl_xor(s, off);
            row[lane] = e0;
            if (hi) row[lane + 64] = e1;
            if (lane == 0) rsum[r] = 1.0f / s;
        }
    }
    __syncthreads();

    // store P[b][t][h][s] (coalesced s-runs) + fused ap for b==0
    const bool doap = (b == 0);
    for (int idx = tid; idx < nt * Tq; idx += 256) {
        const int tl = idx / Tq, s = idx - tl * Tq;
        const int tg2 = t0g + tl;
        const float mv = msk[((size_t)h * Tq + tg2) * Tq + s];
        const float pm = sc[tl * 85 + s] * rsum[tl] * mv;
        P[(((size_t)b * Tq + tg2) * Hq + h) * PS + s] = pm;
        if (doap) out[BTD + ((size_t)tg2 * Tq + s) * Hq + h] = pm - 1.0f + mv;
    }
}

// ---------------------------------------------------------------------------
// K3: bo einsum + quick-gelu + fanout + residual. grid (11, 16) = (t-chunk8, b),
// block 512 = 8 waves; wave w = head w, lanes = d/2 (one wave V read = one
// contiguous 512B row, V layout [b][h][s][d]). P tile [8t][8h][84s] staged
// contiguously; s blocked by 4. 8-way LDS reduce -> gelu -> fanout.
// ---------------------------------------------------------------------------
__global__ __launch_bounds__(512) void k_out(
    const float* __restrict__ x, const float* __restrict__ P,
    const float* __restrict__ V, const float* __restrict__ fw,
    const float* __restrict__ fb, float* __restrict__ out)
{
    __shared__ float Pl[8][Hq][PS];          // 21.5 KB
    __shared__ float bo_part[8][8][128];     // 32 KB
    __shared__ float zs[8][128];             // 4 KB
    const int tid = threadIdx.x;
    const int t0 = blockIdx.x * 8, b = blockIdx.y;

    // stage P tile: 5376 contiguous floats (last block over-reads into Q
    // region — finite, masked at store)
    {
        const float4* src = (const float4*)(P + ((size_t)b * Tq + t0) * Hq * PS);
        #pragma unroll
        for (int idx = tid; idx < 8 * Hq * PS / 4; idx += 512)
            ((float4*)Pl)[idx] = src[idx];
    }
    __syncthreads();

    const int w = tid >> 6, lane = tid & 63;   // w = head
    {
        const int d0 = lane * 2;
        float2 acc[8];
        #pragma unroll
        for (int i = 0; i < 8; ++i) acc[i] = make_float2(0.f, 0.f);
        const float* vp = V + (((size_t)b * Hq + w) * Tq) * Dq + d0;
        for (int s4 = 0; s4 < 20; ++s4) {
            float4 p[8];
            #pragma unroll
            for (int t = 0; t < 8; ++t)
                p[t] = *(const float4*)(&Pl[t][w][s4 * 4]);
            #pragma unroll
            for (int ss = 0; ss < 4; ++ss) {
                const int s = s4 * 4 + ss;
                const float2 vv = *(const float2*)(vp + (size_t)s * Dq);
                #pragma unroll
                for (int t = 0; t < 8; ++t) {
                    const float pv = ((const float*)&p[t])[ss];
                    acc[t].x = fmaf(pv, vv.x, acc[t].x);
                    acc[t].y = fmaf(pv, vv.y, acc[t].y);
                }
            }
        }
        {   // tail s = 80
            const float2 vv = *(const float2*)(vp + (size_t)80 * Dq);
            #pragma unroll
            for (int t = 0; t < 8; ++t) {
                const float pv = Pl[t][w][80];
                acc[t].x = fmaf(pv, vv.x, acc[t].x);
                acc[t].y = fmaf(pv, vv.y, acc[t].y);
            }
        }
        #pragma unroll
        for (int t = 0; t < 8; ++t) {
            bo_part[w][t][d0]     = acc[t].x;
            bo_part[w][t][d0 + 1] = acc[t].y;
        }
    }
    __syncthreads();

    #pragma unroll
    for (int idx = tid; idx < 1024; idx += 512) {   // gelu: 8t x 128d
        const int t = idx >> 7, d = idx & 127;
        float bo = 0.f;
        #pragma unroll
        for (int ww = 0; ww < 8; ++ww) bo += bo_part[ww][t][d];
        const float tt = bo + 4.0f;
        const float sg = 1.0f / (1.0f + __expf(-1.702f * tt));
        zs[t][d] = tt * sg - 4.0f;
    }
    __syncthreads();

    {   // fanout: thread -> (n = tid&127), t in {tg, tg+4}; fw row shared
        const int n = tid & 127, tg = tid >> 7;
        const float* fwr = fw + (size_t)n * Dq;
        const float fbn = fb[n];
        float a0 = 0.f, a1 = 0.f;
        #pragma unroll 8
        for (int k4 = 0; k4 < 32; ++k4) {
            const float4 w4 = *(const float4*)(fwr + k4 * 4);
            const float4 z0 = *(const float4*)(&zs[tg][k4 * 4]);
            const float4 z1 = *(const float4*)(&zs[tg + 4][k4 * 4]);
            a0 += z0.x * w4.x + z0.y * w4.y + z0.z * w4.z + z0.w * w4.w;
            a1 += z1.x * w4.x + z1.y * w4.y + z1.z * w4.z + z1.w * w4.w;
        }
        const int t1 = t0 + tg, t2 = t0 + tg + 4;
        if (t1 < Tq) {
            const size_t o = ((size_t)b * Tq + t1) * Dq + n;
            out[o] = x[o] + a0 + fbn;
        }
        if (t2 < Tq) {
            const size_t o = ((size_t)b * Tq + t2) * Dq + n;
            out[o] = x[o] + a1 + fbn;
        }
    }
}

extern "C" void kernel_launch(void* const* d_in, const int* in_sizes, int n_in,
                              void* d_out, int out_size, void* d_ws, size_t ws_size,
                              hipStream_t stream) {
    const float* x        = (const float*)d_in[0];
    const float* msk      = (const float*)d_in[1];
    const float* wqkv_w   = (const float*)d_in[2];
    const float* wqkv_b   = (const float*)d_in[3];
    const float* wk_w     = (const float*)d_in[4];
    const float* fanout_w = (const float*)d_in[5];
    const float* fanout_b = (const float*)d_in[6];
    const float* he       = (const float*)d_in[7];
    float* out = (float*)d_out;
    float* ws  = (float*)d_ws;

    float* P   = ws + P_OFF;
    float* Q   = ws + Q_OFF;
    float* V   = ws + V_OFF;

    k_qkv_mfma<<<dim3(21, 32), 256, 0, stream>>>(x, wqkv_w, wqkv_b, he, Q, V);
    k_scores<<<dim3(4, 8, 16), 256, 0, stream>>>(x, Q, wk_w, msk, P, out);
    k_out<<<dim3(11, 16), 512, 0, stream>>>(x, P, V, fanout_w, fanout_b, out);
}

// Round 9
// 124.678 us; speedup vs baseline: 1.0851x; 1.0118x over previous
//
#include <hip/hip_runtime.h>
#include <math.h>

#define Bq 16
#define Tq 81
#define Dq 128
#define Hq 8
#define BT (Bq*Tq)          // 1296
#define BTD (Bq*Tq*Dq)      // 165888 (out region 0)
#define PS 84               // padded s-stride of P
// ws layout (floats). P: [b][t][h][s(pad 84)]; Q: [b][h][t][d] f32;
// V: [b][h][s][d] bf16 (ushort) in the V_OFF region.
#define P_SZ   (Bq*Tq*Hq*PS)        // 870912
#define QV_SZ  (BT*Hq*Dq)           // 1327104
#define P_OFF  0
#define Q_OFF  (P_OFF + P_SZ)
#define V_OFF  (Q_OFF + QV_SZ)

#define LSTR 136            // k_qkv LDS row stride (ushorts): 16B-aligned rows

typedef __attribute__((ext_vector_type(8))) short short8;
typedef __attribute__((ext_vector_type(4))) float f32x4;

__device__ __forceinline__ float l1_4(const float4 q, const float4 k) {
    return fabsf(q.x - k.x) + fabsf(q.y - k.y) + fabsf(q.z - k.z) + fabsf(q.w - k.w);
}
__device__ __forceinline__ int imin(int a, int b) { return a < b ? a : b; }
__device__ __forceinline__ unsigned short f2bf(float f) {   // RNE f32 -> bf16
    unsigned u = __float_as_uint(f);
    u += 0x7fffu + ((u >> 16) & 1u);
    return (unsigned short)(u >> 16);
}
__device__ __forceinline__ float bf2f(unsigned short s) {
    return __uint_as_float((unsigned)s << 16);
}

// ---------------------------------------------------------------------------
// K1: QKV GEMM via bf16 MFMA 16x16x32. grid (21, 32), 256 thr = 4 waves.
// f32->bf16 cvt once per block into LDS (in-loop cvt regressed in R7).
// Block: 64 m-rows x 64 W-rows. Wave w: local m-tile w, 4 n-tiles.
// C/D: col=lane&15, row=quad*4+reg. Epilogue: +bias; Q -> f32 [b][h][t][d];
// V -> *he, bf16 [b][h][s][d] (halves K3's V traffic).
// ---------------------------------------------------------------------------
__global__ __launch_bounds__(256) void k_qkv_mfma(
    const float* __restrict__ x, const float* __restrict__ wqkv,
    const float* __restrict__ bias, const float* __restrict__ he,
    float* __restrict__ Qo, unsigned short* __restrict__ Vb)
{
    __shared__ unsigned short xs[64 * LSTR];    // 17.4 KB
    __shared__ unsigned short wsh[64 * LSTR];   // 17.4 KB
    const int tid = threadIdx.x;
    const int w = tid >> 6, lane = tid & 63;
    const int ln = lane & 15, quad = lane >> 4;
    const int r0 = blockIdx.x * 64;               // m-row base (bx 0..20)
    const int n0 = blockIdx.y * 64;               // W-row base
    const int h  = blockIdx.y >> 2;
    const int isV = (blockIdx.y >> 1) & 1;
    const int c0 = (blockIdx.y & 1) * 64;

    // stage + cvt: 64 x-rows and 64 W-rows (8 float4/thread each)
    #pragma unroll
    for (int i = 0; i < 8; ++i) {
        const int idx = tid + i * 256;            // 0..2047
        const int r = idx >> 5, c4 = idx & 31;
        const int gr = imin(r0 + r, BT - 1);      // clamp tail rows
        const float4 v = *(const float4*)(x + (size_t)gr * Dq + c4 * 4);
        ushort4 o;
        o.x = f2bf(v.x); o.y = f2bf(v.y); o.z = f2bf(v.z); o.w = f2bf(v.w);
        *(ushort4*)(&xs[r * LSTR + c4 * 4]) = o;

        const float4 vw = *(const float4*)(wqkv + (size_t)(n0 + r) * Dq + c4 * 4);
        ushort4 ow;
        ow.x = f2bf(vw.x); ow.y = f2bf(vw.y); ow.z = f2bf(vw.z); ow.w = f2bf(vw.w);
        *(ushort4*)(&wsh[r * LSTR + c4 * 4]) = ow;
    }
    __syncthreads();

    const unsigned short* xa = xs + (w * 16 + ln) * LSTR + quad * 8;
    const unsigned short* wb = wsh + ln * LSTR + quad * 8;

    f32x4 acc[4];
    #pragma unroll
    for (int i = 0; i < 4; ++i) acc[i] = (f32x4){0.f, 0.f, 0.f, 0.f};

    #pragma unroll
    for (int kb = 0; kb < Dq; kb += 32) {
        const short8 af = *(const short8*)(xa + kb);
        #pragma unroll
        for (int nt = 0; nt < 4; ++nt) {
            const short8 bf = *(const short8*)(wb + nt * 16 * LSTR + kb);
            acc[nt] = __builtin_amdgcn_mfma_f32_16x16x32_bf16(af, bf, acc[nt], 0, 0, 0);
        }
    }

    const float scale = isV ? he[h] : 1.0f;
    const int gm0 = r0 + w * 16 + quad * 4;
    #pragma unroll
    for (int nt = 0; nt < 4; ++nt) {
        const float bn = bias[n0 + nt * 16 + ln];
        #pragma unroll
        for (int r = 0; r < 4; ++r) {
            const int gm = gm0 + r;
            if (gm < BT) {
                const int bb = gm / 81, tt = gm - bb * 81;
                const size_t o =
                    (((size_t)bb * Hq + h) * Tq + tt) * Dq + c0 + nt * 16 + ln;
                const float val = (acc[nt][r] + bn) * scale;
                if (isV) Vb[o] = f2bf(val);
                else     Qo[o] = val;
            }
        }
    }
}

// ---------------------------------------------------------------------------
// K2: scores + softmax + P (+ap for b==0). grid (4, 8, 16) = (tq, h, b),
// block 256. K = x*wk in LDS (81x132). Compute: 243 threads = 3 tg (7t) x
// 81 sg (1s) -> 1 ds_read_b128 per k4 per thread, q loads wave-broadcast.
// Wave-parallel softmax. P store [b][t][h][s] coalesced; ap fused for b==0.
// ---------------------------------------------------------------------------
__global__ __launch_bounds__(256) void k_scores(
    const float* __restrict__ x, const float* __restrict__ Q,
    const float* __restrict__ wk, const float* __restrict__ msk,
    float* __restrict__ P, float* __restrict__ out)
{
    __shared__ float Kl[81 * 132];
    __shared__ float sc[21 * 85];
    __shared__ float rsum[24];
    const int tid = threadIdx.x;
    const int tq = blockIdx.x, h = blockIdx.y, b = blockIdx.z;
    const int t0g = tq * 21;
    const int nt = (tq == 3) ? 18 : 21;

    // stage K = x * wk[h]  (81 rows x 128, row stride 132)
    {
        const float* wkb = wk + (size_t)h * Dq;
        for (int idx = tid; idx < Tq * 32; idx += 256) {
            const int r = idx >> 5, c = idx & 31;
            const float4 xv = *(const float4*)(x + (size_t)(b * Tq + r) * Dq + c * 4);
            const float4 wv = *(const float4*)(wkb + c * 4);
            float4 kv;
            kv.x = xv.x * wv.x; kv.y = xv.y * wv.y;
            kv.z = xv.z * wv.z; kv.w = xv.w * wv.w;
            *(float4*)(&Kl[r * 132 + c * 4]) = kv;
        }
    }
    __syncthreads();

    if (tid < 243) {
        const int tg = tid / 81, sg = tid % 81;   // tg 0..2, sg = s
        const float* qrow[7];
        #pragma unroll
        for (int i = 0; i < 7; ++i) {
            const int t = imin(t0g + tg * 7 + i, Tq - 1);
            qrow[i] = Q + (((size_t)b * Hq + h) * Tq + t) * Dq;
        }
        float acc[7];
        #pragma unroll
        for (int i = 0; i < 7; ++i) acc[i] = 0.f;

        #pragma unroll 4
        for (int k4 = 0; k4 < 32; ++k4) {
            const float4 kv = *(const float4*)(&Kl[sg * 132 + k4 * 4]);
            #pragma unroll
            for (int i = 0; i < 7; ++i) {
                const float4 qv = *(const float4*)(qrow[i] + k4 * 4);
                acc[i] += l1_4(qv, kv);
            }
        }
        const float ns = -0.08838834764831845f;   // -1/sqrt(128)
        #pragma unroll
        for (int i = 0; i < 7; ++i)
            sc[(tg * 7 + i) * 85 + sg] = acc[i] * ns;
    }
    __syncthreads();

    // wave-parallel softmax: wave w handles rows w, w+4, ...
    {
        const int w = tid >> 6, lane = tid & 63;
        for (int r = w; r < nt; r += 4) {
            float* row = sc + r * 85;
            const bool hi = (lane + 64) < Tq;
            const float v0 = row[lane];
            const float v1 = hi ? row[lane + 64] : -1e30f;
            float m = fmaxf(v0, v1);
            #pragma unroll
            for (int off = 32; off > 0; off >>= 1)
                m = fmaxf(m, __shfl_xor(m, off));
            const float e0 = __expf(v0 - m);
            const float e1 = hi ? __expf(v1 - m) : 0.f;
            float s = e0 + e1;
            #pragma unroll
            for (int off = 32; off > 0; off >>= 1)
                s += __shfl_xor(s, off);
            row[lane] = e0;
            if (hi) row[lane + 64] = e1;
            if (lane == 0) rsum[r] = 1.0f / s;
        }
    }
    __syncthreads();

    // store P[b][t][h][s] (coalesced s-runs) + fused ap for b==0
    const bool doap = (b == 0);
    for (int idx = tid; idx < nt * Tq; idx += 256) {
        const int tl = idx / Tq, s = idx - tl * Tq;
        const int tg2 = t0g + tl;
        const float mv = msk[((size_t)h * Tq + tg2) * Tq + s];
        const float pm = sc[tl * 85 + s] * rsum[tl] * mv;
        P[(((size_t)b * Tq + tg2) * Hq + h) * PS + s] = pm;
        if (doap) out[BTD + ((size_t)tg2 * Tq + s) * Hq + h] = pm - 1.0f + mv;
    }
}

// ---------------------------------------------------------------------------
// K3: bo einsum + quick-gelu + fanout + residual. grid (14, 16) = (t-chunk6, b)
// = 224 blocks (87.5% CU coverage; was 176/69%), block 512 = 8 waves; wave w =
// head w, lanes = d/2. V read as bf16 ushort2 (half the bytes of R8).
// P tile [6t][8h][84s] staged contiguously; s blocked by 4. 8-way LDS reduce
// -> gelu -> fanout (fw row loaded once per k4, reused).
// ---------------------------------------------------------------------------
__global__ __launch_bounds__(512) void k_out(
    const float* __restrict__ x, const float* __restrict__ P,
    const unsigned short* __restrict__ Vb, const float* __restrict__ fw,
    const float* __restrict__ fb, float* __restrict__ out)
{
    __shared__ float Pl[6][Hq][PS];          // 15.75 KB
    __shared__ float bo_part[8][6][128];     // 24 KB
    __shared__ float zs[6][128];             // 3 KB
    const int tid = threadIdx.x;
    const int t0 = blockIdx.x * 6, b = blockIdx.y;

    // stage P tile: 4032 contiguous floats (last blocks over-read into Q
    // region — finite, masked at store)
    {
        const float4* src = (const float4*)(P + ((size_t)b * Tq + t0) * Hq * PS);
        #pragma unroll
        for (int idx = tid; idx < 6 * Hq * PS / 4; idx += 512)
            ((float4*)Pl)[idx] = src[idx];
    }
    __syncthreads();

    const int w = tid >> 6, lane = tid & 63;   // w = head
    {
        const int d0 = lane * 2;
        float2 acc[6];
        #pragma unroll
        for (int i = 0; i < 6; ++i) acc[i] = make_float2(0.f, 0.f);
        const unsigned short* vp = Vb + (((size_t)b * Hq + w) * Tq) * Dq + d0;
        for (int s4 = 0; s4 < 20; ++s4) {
            float4 p[6];
            #pragma unroll
            for (int t = 0; t < 6; ++t)
                p[t] = *(const float4*)(&Pl[t][w][s4 * 4]);
            #pragma unroll
            for (int ss = 0; ss < 4; ++ss) {
                const int s = s4 * 4 + ss;
                const ushort2 uv = *(const ushort2*)(vp + (size_t)s * Dq);
                const float vx = bf2f(uv.x), vy = bf2f(uv.y);
                #pragma unroll
                for (int t = 0; t < 6; ++t) {
                    const float pv = ((const float*)&p[t])[ss];
                    acc[t].x = fmaf(pv, vx, acc[t].x);
                    acc[t].y = fmaf(pv, vy, acc[t].y);
                }
            }
        }
        {   // tail s = 80
            const ushort2 uv = *(const ushort2*)(vp + (size_t)80 * Dq);
            const float vx = bf2f(uv.x), vy = bf2f(uv.y);
            #pragma unroll
            for (int t = 0; t < 6; ++t) {
                const float pv = Pl[t][w][80];
                acc[t].x = fmaf(pv, vx, acc[t].x);
                acc[t].y = fmaf(pv, vy, acc[t].y);
            }
        }
        #pragma unroll
        for (int t = 0; t < 6; ++t) {
            bo_part[w][t][d0]     = acc[t].x;
            bo_part[w][t][d0 + 1] = acc[t].y;
        }
    }
    __syncthreads();

    for (int idx = tid; idx < 768; idx += 512) {   // gelu: 6t x 128d
        const int t = idx >> 7, d = idx & 127;
        float bo = 0.f;
        #pragma unroll
        for (int ww = 0; ww < 8; ++ww) bo += bo_part[ww][t][d];
        const float tt = bo + 4.0f;
        const float sg = 1.0f / (1.0f + __expf(-1.702f * tt));
        zs[t][d] = tt * sg - 4.0f;
    }
    __syncthreads();

    {   // fanout: thread -> (n = tid&127), t in {tg, tg+4 (tg<2)}; fw shared
        const int n = tid & 127, tg = tid >> 7;   // tg 0..3
        const bool two = (tg < 2);
        const int tB = two ? tg + 4 : tg;          // dummy=tg when !two
        const float* fwr = fw + (size_t)n * Dq;
        const float fbn = fb[n];
        float a0 = 0.f, a1 = 0.f;
        #pragma unroll 8
        for (int k4 = 0; k4 < 32; ++k4) {
            const float4 w4 = *(const float4*)(fwr + k4 * 4);
            const float4 z0 = *(const float4*)(&zs[tg][k4 * 4]);
            const float4 z1 = *(const float4*)(&zs[tB][k4 * 4]);
            a0 += z0.x * w4.x + z0.y * w4.y + z0.z * w4.z + z0.w * w4.w;
            a1 += z1.x * w4.x + z1.y * w4.y + z1.z * w4.z + z1.w * w4.w;
        }
        const int t1 = t0 + tg;
        if (t1 < Tq) {
            const size_t o = ((size_t)b * Tq + t1) * Dq + n;
            out[o] = x[o] + a0 + fbn;
        }
        const int t2 = t0 + tg + 4;
        if (two && t2 < Tq) {
            const size_t o = ((size_t)b * Tq + t2) * Dq + n;
            out[o] = x[o] + a1 + fbn;
        }
    }
}

extern "C" void kernel_launch(void* const* d_in, const int* in_sizes, int n_in,
                              void* d_out, int out_size, void* d_ws, size_t ws_size,
                              hipStream_t stream) {
    const float* x        = (const float*)d_in[0];
    const float* msk      = (const float*)d_in[1];
    const float* wqkv_w   = (const float*)d_in[2];
    const float* wqkv_b   = (const float*)d_in[3];
    const float* wk_w     = (const float*)d_in[4];
    const float* fanout_w = (const float*)d_in[5];
    const float* fanout_b = (const float*)d_in[6];
    const float* he       = (const float*)d_in[7];
    float* out = (float*)d_out;
    float* ws  = (float*)d_ws;

    float* P  = ws + P_OFF;
    float* Q  = ws + Q_OFF;
    unsigned short* Vb = (unsigned short*)(ws + V_OFF);

    k_qkv_mfma<<<dim3(21, 32), 256, 0, stream>>>(x, wqkv_w, wqkv_b, he, Q, Vb);
    k_scores<<<dim3(4, 8, 16), 256, 0, stream>>>(x, Q, wk_w, msk, P, out);
    k_out<<<dim3(14, 16), 512, 0, stream>>>(x, P, Vb, fanout_w, fanout_b, out);
}